// Round 1
// 539.846 us; speedup vs baseline: 1.0772x; 1.0772x over previous
//
#include <hip/hip_runtime.h>

// out[e] = segment_sum(M, dest)[src[e]] - M[rev_index[e]]
// E = 800,000, D = 64 (fp32), N_NODES = 50,000.
// Pipeline: counting-sort CSR (int atomics only) -> one-wave-per-node segmented
// reduction -> gather-subtract with nontemporal output stores.

#define D 64
#define N_NODES 50000
#define SCAN_THREADS 1024

typedef float f4 __attribute__((ext_vector_type(4)));

// K1: histogram of dest, 4 edges/thread via int4.
__global__ void agg_hist(const int* __restrict__ dest, int* __restrict__ counts, int E) {
    int t = blockIdx.x * blockDim.x + threadIdx.x;
    int e = t << 2;
    if (e + 3 < E) {
        int4 d = *reinterpret_cast<const int4*>(dest + e);
        atomicAdd(counts + d.x, 1);
        atomicAdd(counts + d.y, 1);
        atomicAdd(counts + d.z, 1);
        atomicAdd(counts + d.w, 1);
    } else {
        for (; e < E; ++e) atomicAdd(counts + dest[e], 1);
    }
}

// K2: single-block exclusive scan, coalesced tiled version.
// Writes scanned offsets in place AND a second copy into cursor (kills the D2D memcpy).
__global__ void agg_scan(int* __restrict__ data, int* __restrict__ cursor) {
    __shared__ int wsums[SCAN_THREADS / 64];
    __shared__ int carry_sh;
    const int t = threadIdx.x;
    const int lane = t & 63;
    const int w = t >> 6;
    if (t == 0) carry_sh = 0;
    __syncthreads();
    for (int base = 0; base < N_NODES; base += SCAN_THREADS) {
        int i = base + t;
        int v = (i < N_NODES) ? data[i] : 0;   // coalesced
        int carry = carry_sh;                  // stable until t0 writes after barrier A
        // inclusive wave scan
        int x = v;
        #pragma unroll
        for (int off = 1; off < 64; off <<= 1) {
            int y = __shfl_up(x, off, 64);
            if (lane >= off) x += y;
        }
        if (lane == 63) wsums[w] = x;
        __syncthreads();                       // A
        if (t == 0) {
            int run = 0;
            #pragma unroll
            for (int k = 0; k < SCAN_THREADS / 64; ++k) {
                int c = wsums[k]; wsums[k] = run; run += c;
            }
            carry_sh = carry + run;
        }
        __syncthreads();                       // B
        int excl = carry + wsums[w] + (x - v);
        if (i < N_NODES) { data[i] = excl; cursor[i] = excl; }
        __syncthreads();                       // C: protect wsums/carry_sh for next tile
    }
    if (t == 0) { data[N_NODES] = carry_sh; cursor[N_NODES] = carry_sh; }
}

// K3: bin edge ids by dest, 4 edges/thread.
__global__ void agg_bin(const int* __restrict__ dest, int* __restrict__ cursor,
                        int* __restrict__ order, int E) {
    int t = blockIdx.x * blockDim.x + threadIdx.x;
    int e = t << 2;
    if (e + 3 < E) {
        int4 d = *reinterpret_cast<const int4*>(dest + e);
        int p0 = atomicAdd(cursor + d.x, 1); order[p0] = e;
        int p1 = atomicAdd(cursor + d.y, 1); order[p1] = e + 1;
        int p2 = atomicAdd(cursor + d.z, 1); order[p2] = e + 2;
        int p3 = atomicAdd(cursor + d.w, 1); order[p3] = e + 3;
    } else {
        for (; e < E; ++e) {
            int pos = atomicAdd(cursor + dest[e], 1);
            order[pos] = e;
        }
    }
}

// K4: one wave per node; lane = feature dim. 8 independent 256B row loads in flight.
__global__ void agg_reduce(const float* __restrict__ M,
                           const int* __restrict__ order,
                           const int* __restrict__ offsets,
                           float* __restrict__ Mv) {
    int lane = threadIdx.x & 63;
    int node = (blockIdx.x * blockDim.x + threadIdx.x) >> 6;
    if (node >= N_NODES) return;
    int beg = offsets[node];
    int end = offsets[node + 1];
    float acc0 = 0.f, acc1 = 0.f, acc2 = 0.f, acc3 = 0.f;
    int i = beg;
    for (; i + 8 <= end; i += 8) {
        int e0 = order[i + 0], e1 = order[i + 1], e2 = order[i + 2], e3 = order[i + 3];
        int e4 = order[i + 4], e5 = order[i + 5], e6 = order[i + 6], e7 = order[i + 7];
        float a0 = M[(size_t)e0 * D + lane];
        float a1 = M[(size_t)e1 * D + lane];
        float a2 = M[(size_t)e2 * D + lane];
        float a3 = M[(size_t)e3 * D + lane];
        float a4 = M[(size_t)e4 * D + lane];
        float a5 = M[(size_t)e5 * D + lane];
        float a6 = M[(size_t)e6 * D + lane];
        float a7 = M[(size_t)e7 * D + lane];
        acc0 += a0 + a4;
        acc1 += a1 + a5;
        acc2 += a2 + a6;
        acc3 += a3 + a7;
    }
    for (; i < end; ++i) acc0 += M[(size_t)order[i] * D + lane];
    Mv[(size_t)node * D + lane] = (acc0 + acc1) + (acc2 + acc3);
}

// K5: out[e] = Mv[src[e]] - M[rev[e]], 16 threads/edge, float4 each.
// Nontemporal stores: out (204.8 MB) is never re-read; keep it out of L2/LLC so
// M (204.8 MB) + Mv (12.8 MB) stay resident in the 256 MiB Infinity Cache and
// M[rev] gathers hit LLC instead of HBM.
__global__ void agg_gather(const float* __restrict__ Mv,
                           const float* __restrict__ M,
                           const int* __restrict__ src,
                           const int* __restrict__ rev,
                           float* __restrict__ out,
                           int E) {
    int gid = blockIdx.x * blockDim.x + threadIdx.x;
    int e  = gid >> 4;
    int c4 = gid & 15;
    if (e >= E) return;
    int s = src[e];
    int r = rev[e];
    f4 a = reinterpret_cast<const f4*>(Mv + (size_t)s * D)[c4];
    f4 b = reinterpret_cast<const f4*>(M  + (size_t)r * D)[c4];
    f4 o = a - b;
    __builtin_nontemporal_store(o, reinterpret_cast<f4*>(out + (size_t)e * D) + c4);
}

extern "C" void kernel_launch(void* const* d_in, const int* in_sizes, int n_in,
                              void* d_out, int out_size, void* d_ws, size_t ws_size,
                              hipStream_t stream) {
    const float* M   = (const float*)d_in[0];
    const int*   ei  = (const int*)d_in[1];   // (2, E) row-major: [src | dest]
    const int*   rev = (const int*)d_in[2];

    int E = in_sizes[0] / D;                  // 800,000
    const int* src  = ei;
    const int* dest = ei + E;

    // Workspace layout (256B-aligned chunks)
    int*   offsets = (int*)d_ws;                       // 50,001 ints (counts -> scan in place)
    int*   cursor  = offsets + 50304;                  // 50,001 ints
    int*   order   = cursor + 50304;                   // 800,000 ints
    float* Mv      = (float*)(order + 800128);         // 50,000*64 floats = 12.8 MB

    hipMemsetAsync(offsets, 0, (N_NODES + 1) * sizeof(int), stream);

    int hb = ((E + 3) / 4 + 255) / 256;
    agg_hist<<<hb, 256, 0, stream>>>(dest, offsets, E);
    agg_scan<<<1, SCAN_THREADS, 0, stream>>>(offsets, cursor);
    agg_bin<<<hb, 256, 0, stream>>>(dest, cursor, order, E);

    int rb = (N_NODES * 64 + 255) / 256;      // one wave per node
    agg_reduce<<<rb, 256, 0, stream>>>(M, order, offsets, Mv);

    int gb = (E * 16 + 255) / 256;
    agg_gather<<<gb, 256, 0, stream>>>(Mv, M, src, rev, (float*)d_out, E);
}